// Round 1
// baseline (986.328 us; speedup 1.0000x reference)
//
#include <hip/hip_runtime.h>
#include <hip/hip_bf16.h>
#include <math.h>

typedef unsigned short u16;
typedef __attribute__((ext_vector_type(8))) __bf16 bf16x8;
typedef __attribute__((ext_vector_type(4))) float f32x4;

__device__ __forceinline__ u16 f2b(float f) {
  unsigned u = __builtin_bit_cast(unsigned, f);
  u += 0x7fffu + ((u >> 16) & 1u);
  return (u16)(u >> 16);
}
__device__ __forceinline__ float b2f(u16 h) {
  unsigned u = ((unsigned)h) << 16;
  return __builtin_bit_cast(float, u);
}

__device__ __forceinline__ void gld_lds16(const u16* g, u16* l) {
  __builtin_amdgcn_global_load_lds(
      (const __attribute__((address_space(1))) unsigned int*)g,
      (__attribute__((address_space(3))) unsigned int*)l, 16, 0, 0);
}

// ---------------- generic 128x128 BT-form GEMM tile body (m97 structure) ----
// C[m][n] = sum_k A[m][k] * B[n][k], K multiple of 64, tiles 128x128, 256 thr.
template <class FA, class FB, class FC>
__device__ __forceinline__ void gemm128_body(FA fa, FB fb, FC fc, int m0,
                                             int n0, int K) {
  __shared__ __align__(16) u16 As[128 * 64];
  __shared__ __align__(16) u16 Bs[128 * 64];
  const int tid = threadIdx.x;
  const int wave = tid >> 6;
  const int lane = tid & 63;
  const int srow = lane >> 3;        // 0..7
  const int scol = (lane & 7) * 8;   // element offset (16B chunks)
  const int wm = (wave & 1) * 64;
  const int wn = (wave >> 1) * 64;
  const int fm = lane & 15;
  const int fr = (lane >> 4) * 8;

  f32x4 acc[4][4];
#pragma unroll
  for (int i = 0; i < 4; ++i)
#pragma unroll
    for (int j = 0; j < 4; ++j) acc[i][j] = (f32x4){0.f, 0.f, 0.f, 0.f};

  for (int k0 = 0; k0 < K; k0 += 64) {
#pragma unroll
    for (int c = 0; c < 4; ++c) {
      int chunk = c * 4 + wave;  // 0..15, wave-uniform
      int row = chunk * 8 + srow;
      gld_lds16(fa(m0 + row, k0 + scol), &As[chunk * 512]);
      gld_lds16(fb(n0 + row, k0 + scol), &Bs[chunk * 512]);
    }
    __syncthreads();
#pragma unroll
    for (int kk = 0; kk < 2; ++kk) {
      bf16x8 af[4], bfr[4];
#pragma unroll
      for (int i = 0; i < 4; ++i)
        af[i] = *(const bf16x8*)&As[(wm + i * 16 + fm) * 64 + kk * 32 + fr];
#pragma unroll
      for (int j = 0; j < 4; ++j)
        bfr[j] = *(const bf16x8*)&Bs[(wn + j * 16 + fm) * 64 + kk * 32 + fr];
#pragma unroll
      for (int i = 0; i < 4; ++i)
#pragma unroll
        for (int j = 0; j < 4; ++j)
          acc[i][j] = __builtin_amdgcn_mfma_f32_16x16x32_bf16(
              af[i], bfr[j], acc[i][j], 0, 0, 0);
    }
    __syncthreads();
  }
  const int er = lane >> 4;
#pragma unroll
  for (int i = 0; i < 4; ++i)
#pragma unroll
    for (int j = 0; j < 4; ++j)
#pragma unroll
      for (int r = 0; r < 4; ++r) {
        int m = m0 + wm + i * 16 + er * 4 + r;
        int n = n0 + wn + j * 16 + fm;
        fc(m, n, acc[i][j][r]);
      }
}

// ---------------- functors ----------------
struct FAB {
  const u16* p;
  int ld;
  __device__ __forceinline__ const u16* operator()(int r, int k) const {
    return p + (size_t)r * ld + k;
  }
};
// vh stored in q-buffer layout [B,H,L,Dh]; gather row m=(b,l), col k=h*1024+d
struct FAvh {
  const u16* q;
  __device__ __forceinline__ const u16* operator()(int m, int k) const {
    int b = m >> 11, l = m & 2047, h = k >> 10, kk = k & 1023;
    return q + ((size_t)((b << 1) + h) * 2048 + l) * 1024 + kk;
  }
};
struct EQKV {
  u16* qb;
  u16* kb;
  float* vout;
  const float* bias;
  __device__ __forceinline__ void operator()(int m, int n, float v) const {
    v += bias[n];
    int b = m >> 11, l = m & 2047;
    int part = n >> 11, nn = n & 2047, h = nn >> 10, d = nn & 1023;
    size_t idx = ((size_t)((b << 1) + h) * 2048 + l) * 1024 + d;
    if (part == 0)
      qb[idx] = f2b(v);
    else if (part == 1)
      kb[idx] = f2b(v);
    else
      vout[idx] = v;
  }
};
struct EScore {
  float* S;
  __device__ __forceinline__ void operator()(int m, int n, float v) const {
    S[((size_t)m << 11) + n] = v * 0.03125f + (n > m ? -1.0e9f : 0.0f);
  }
};
struct EBf16 {
  u16* o;
  int ld;
  __device__ __forceinline__ void operator()(int m, int n, float v) const {
    o[(size_t)m * ld + n] = f2b(v);
  }
};
struct EOut {
  float* o;
  const float* bias;
  __device__ __forceinline__ void operator()(int m, int n, float v) const {
    o[((size_t)m << 11) + n] = v + bias[n];
  }
};

// ---------------- kernels ----------------
__global__ void __launch_bounds__(256) k_cast(const float* in, u16* out) {
  int i = (blockIdx.x * 256 + threadIdx.x) * 4;
  float4 f = *(const float4*)(in + i);
  ushort4 o;
  o.x = f2b(f.x);
  o.y = f2b(f.y);
  o.z = f2b(f.z);
  o.w = f2b(f.w);
  *(ushort4*)(out + i) = o;
}

__global__ void __launch_bounds__(256) k_qkv(const u16* xb, const u16* wb,
                                             const float* bias, u16* qb,
                                             u16* kb, float* vout) {
  gemm128_body(FAB{xb, 2048}, FAB{wb, 2048}, EQKV{qb, kb, vout, bias},
               blockIdx.y * 128, blockIdx.x * 128, 2048);
}

__global__ void __launch_bounds__(256) k_rope(u16* qb, u16* kb, float* kout) {
  int row = blockIdx.x;  // bh*2048 + l
  int l = row & 2047;
  size_t base = (size_t)row * 1024;
  float lf = (float)l;
  const float c0 = (float)(-9.210340371976184 / 1024.0);  // -ln(1e4)/1024
  for (int i = threadIdx.x; i < 512; i += 256) {
    float inv = expf((float)(2 * i) * c0);
    float th = lf * inv;
    float c = cosf(th), s = sinf(th);
    float x1 = b2f(qb[base + i]), x2 = b2f(qb[base + 512 + i]);
    qb[base + i] = f2b(x1 * c - x2 * s);
    qb[base + 512 + i] = f2b(x1 * s + x2 * c);
    float y1 = b2f(kb[base + i]), y2 = b2f(kb[base + 512 + i]);
    float r1 = y1 * c - y2 * s, r2 = y1 * s + y2 * c;
    kb[base + i] = f2b(r1);
    kb[base + 512 + i] = f2b(r2);
    kout[base + i] = r1;
    kout[base + 512 + i] = r2;
  }
}

__global__ void __launch_bounds__(256) k_transpose_v(const float* v, u16* vt) {
  __shared__ u16 tile[64][65];
  int bh = blockIdx.z;
  int d0 = blockIdx.x * 64, l0 = blockIdx.y * 64;
  const float* vb = v + (size_t)bh * 2048 * 1024;
  u16* vtb = vt + (size_t)bh * 1024 * 2048;
  int t = threadIdx.x;
  int c = t & 63, r4 = t >> 6;
#pragma unroll
  for (int r = 0; r < 16; ++r) {
    int row = r * 4 + r4;
    tile[row][c] = f2b(vb[(size_t)(l0 + row) * 1024 + d0 + c]);
  }
  __syncthreads();
#pragma unroll
  for (int r = 0; r < 16; ++r) {
    int drow = r * 4 + r4;
    vtb[(size_t)(d0 + drow) * 2048 + l0 + c] = tile[c][drow];
  }
}

__global__ void __launch_bounds__(256) k_score(const u16* qb, const u16* kb,
                                               float* S, int zbase) {
  int m0 = blockIdx.y * 128, n0 = blockIdx.x * 128;
  if (n0 > m0) return;  // strictly-upper tile: fully masked, skipped
  int z = blockIdx.z, bh = zbase + z;
  const u16* q = qb + (size_t)bh * 2048 * 1024;
  const u16* k = kb + (size_t)bh * 2048 * 1024;
  float* Sz = S + (size_t)z * 2048 * 2048;
  gemm128_body(FAB{q, 1024}, FAB{k, 1024}, EScore{Sz}, m0, n0, 1024);
}

__global__ void __launch_bounds__(256) k_softmax(const float* S, u16* P) {
  int l = blockIdx.x, z = blockIdx.y;
  const float* Srow = S + ((size_t)z * 2048 + l) * 2048;
  u16* Prow = P + ((size_t)z * 2048 + l) * 2048;
  int t = threadIdx.x;
  int jend = ((l >> 7) + 1) << 7;
  __shared__ float red[4];
  float vals[8];
  float mx = -1e30f;
#pragma unroll
  for (int i = 0; i < 8; ++i) {
    int j = i * 256 + t;
    float v = (j <= l) ? Srow[j] : -1e30f;
    vals[i] = v;
    mx = fmaxf(mx, v);
  }
#pragma unroll
  for (int off = 32; off; off >>= 1) mx = fmaxf(mx, __shfl_down(mx, off));
  if ((t & 63) == 0) red[t >> 6] = mx;
  __syncthreads();
  mx = fmaxf(fmaxf(red[0], red[1]), fmaxf(red[2], red[3]));
  __syncthreads();
  float sum = 0.f;
#pragma unroll
  for (int i = 0; i < 8; ++i) {
    int j = i * 256 + t;
    float e = (j <= l) ? __expf(vals[i] - mx) : 0.f;
    vals[i] = e;
    sum += e;
  }
#pragma unroll
  for (int off = 32; off; off >>= 1) sum += __shfl_down(sum, off);
  if ((t & 63) == 0) red[t >> 6] = sum;
  __syncthreads();
  sum = red[0] + red[1] + red[2] + red[3];
  float is = 1.0f / sum;
#pragma unroll
  for (int i = 0; i < 8; ++i) {
    int j = i * 256 + t;
    if (j < jend) Prow[j] = f2b(vals[i] * is);
  }
}

__global__ void __launch_bounds__(256) k_pv(const u16* P, const u16* vt,
                                            u16* vh, int zbase) {
  int z = blockIdx.z, bh = zbase + z;
  int m0 = blockIdx.y * 128, n0 = blockIdx.x * 128;
  const u16* Pz = P + (size_t)z * 2048 * 2048;
  const u16* vtb = vt + (size_t)bh * 1024 * 2048;
  u16* outb = vh + (size_t)bh * 2048 * 1024;  // overwrites q[bh]: q is dead
  int Keff = m0 + 128;  // causal: P is zero-padded to the tile boundary
  gemm128_body(FAB{Pz, 2048}, FAB{vtb, 2048}, EBf16{outb, 1024}, m0, n0, Keff);
}

__global__ void __launch_bounds__(256) k_out(const u16* vh, const u16* w2,
                                             const float* bias, float* out) {
  gemm128_body(FAvh{vh}, FAB{w2, 2048}, EOut{out, bias}, blockIdx.y * 128,
               blockIdx.x * 128, 2048);
}

// ---------------- launch ----------------
extern "C" void kernel_launch(void* const* d_in, const int* in_sizes, int n_in,
                              void* d_out, int out_size, void* d_ws,
                              size_t ws_size, hipStream_t stream) {
  const float* x = (const float*)d_in[0];
  // d_in[1] = mask: causal 0/-1e9, reproduced analytically in EScore
  const float* w1 = (const float*)d_in[2];
  const float* b1 = (const float*)d_in[3];
  const float* w2 = (const float*)d_in[4];
  const float* b2 = (const float*)d_in[5];
  float* out = (float*)d_out;
  float* kout = out + (size_t)16777216;
  float* vout = kout + (size_t)16777216;

  char* ws = (char*)d_ws;
  u16* xb = (u16*)ws;
  ws += (size_t)33554432;
  u16* w1b = (u16*)ws;
  ws += (size_t)25165824;
  u16* w2b = (u16*)ws;
  ws += (size_t)8388608;
  u16* qb = (u16*)ws;  // doubles as vh after each pair's score GEMM
  ws += (size_t)33554432;
  u16* kb = (u16*)ws;
  ws += (size_t)33554432;
  u16* vtb = (u16*)ws;
  ws += (size_t)33554432;
  size_t used = (size_t)(ws - (char*)d_ws);
  size_t rem = ws_size > used ? ws_size - used : 0;
  size_t perz = (size_t)2048 * 2048 * 4 + (size_t)2048 * 2048 * 2;
  int Z = 1;
  if (rem >= 8 * perz)
    Z = 8;
  else if (rem >= 4 * perz)
    Z = 4;
  else if (rem >= 2 * perz)
    Z = 2;
  float* S = (float*)ws;
  u16* P = (u16*)(ws + (size_t)Z * 2048 * 2048 * 4);

  k_cast<<<16384, 256, 0, stream>>>(x, xb);
  k_cast<<<12288, 256, 0, stream>>>(w1, w1b);
  k_cast<<<4096, 256, 0, stream>>>(w2, w2b);
  k_qkv<<<dim3(48, 64), 256, 0, stream>>>(xb, w1b, b1, qb, kb, vout);
  k_rope<<<16384, 256, 0, stream>>>(qb, kb, kout);
  k_transpose_v<<<dim3(16, 32, 8), 256, 0, stream>>>(vout, vtb);
  for (int zb = 0; zb < 8; zb += Z) {
    k_score<<<dim3(16, 16, Z), 256, 0, stream>>>(qb, kb, S, zb);
    k_softmax<<<dim3(2048, Z), 256, 0, stream>>>(S, P);
    k_pv<<<dim3(8, 16, Z), 256, 0, stream>>>(P, vtb, qb, zb);
  }
  k_out<<<dim3(16, 64), 256, 0, stream>>>(qb, w2b, b2, out);
}

// Round 2
// 896.984 us; speedup vs baseline: 1.0996x; 1.0996x over previous
//
#include <hip/hip_runtime.h>
#include <hip/hip_bf16.h>
#include <math.h>

typedef unsigned short u16;
typedef __attribute__((ext_vector_type(8))) __bf16 bf16x8;
typedef __attribute__((ext_vector_type(4))) float f32x4;

__device__ __forceinline__ u16 f2b(float f) {
  unsigned u = __builtin_bit_cast(unsigned, f);
  u += 0x7fffu + ((u >> 16) & 1u);
  return (u16)(u >> 16);
}
__device__ __forceinline__ float b2f(u16 h) {
  unsigned u = ((unsigned)h) << 16;
  return __builtin_bit_cast(float, u);
}

__device__ __forceinline__ void gld_lds16(const u16* g, u16* l) {
  __builtin_amdgcn_global_load_lds(
      (const __attribute__((address_space(1))) unsigned int*)g,
      (__attribute__((address_space(3))) unsigned int*)l, 16, 0, 0);
}

// ---------------- generic 128x128 BT-form GEMM tile body (m97 structure) ----
// C[m][n] = sum_k A[m][k] * B[n][k], K multiple of 64, tiles 128x128, 256 thr.
// LDS layout is XOR-swizzled: physical 16B-chunk p of row r holds global
// chunk p ^ (r&7). global_load_lds can't pad (wave-uniform base + lane*16),
// so swizzle is the only bank-conflict fix: fragment ds_read_b128 lanes 0..7
// then hit all 8 bank-quads exactly once instead of 8-way colliding on one.
template <class FA, class FB, class FC>
__device__ __forceinline__ void gemm128_body(FA fa, FB fb, FC fc, int m0,
                                             int n0, int K) {
  __shared__ __align__(16) u16 As[128 * 64];
  __shared__ __align__(16) u16 Bs[128 * 64];
  const int tid = threadIdx.x;
  const int wave = tid >> 6;
  const int lane = tid & 63;
  const int srow = lane >> 3;                    // 0..7 row within chunk
  const int scol = ((lane & 7) ^ srow) * 8;      // swizzled global 16B chunk
  const int wm = (wave & 1) * 64;
  const int wn = (wave >> 1) * 64;
  const int fm = lane & 15;
  const int fs = fm & 7;                         // read-side swizzle key

  f32x4 acc[4][4];
#pragma unroll
  for (int i = 0; i < 4; ++i)
#pragma unroll
    for (int j = 0; j < 4; ++j) acc[i][j] = (f32x4){0.f, 0.f, 0.f, 0.f};

  for (int k0 = 0; k0 < K; k0 += 64) {
#pragma unroll
    for (int c = 0; c < 4; ++c) {
      int chunk = c * 4 + wave;  // 0..15, wave-uniform
      int row = chunk * 8 + srow;
      gld_lds16(fa(m0 + row, k0 + scol), &As[chunk * 512]);
      gld_lds16(fb(n0 + row, k0 + scol), &Bs[chunk * 512]);
    }
    __syncthreads();
#pragma unroll
    for (int kk = 0; kk < 2; ++kk) {
      const int cb = kk * 4 + (lane >> 4);       // logical 16B chunk
      const int p8 = (cb ^ fs) * 8;              // physical element offset
      bf16x8 af[4], bfr[4];
#pragma unroll
      for (int i = 0; i < 4; ++i)
        af[i] = *(const bf16x8*)&As[(wm + i * 16 + fm) * 64 + p8];
#pragma unroll
      for (int j = 0; j < 4; ++j)
        bfr[j] = *(const bf16x8*)&Bs[(wn + j * 16 + fm) * 64 + p8];
#pragma unroll
      for (int i = 0; i < 4; ++i)
#pragma unroll
        for (int j = 0; j < 4; ++j)
          acc[i][j] = __builtin_amdgcn_mfma_f32_16x16x32_bf16(
              af[i], bfr[j], acc[i][j], 0, 0, 0);
    }
    __syncthreads();
  }
  const int er = lane >> 4;
#pragma unroll
  for (int i = 0; i < 4; ++i)
#pragma unroll
    for (int j = 0; j < 4; ++j)
#pragma unroll
      for (int r = 0; r < 4; ++r) {
        int m = m0 + wm + i * 16 + er * 4 + r;
        int n = n0 + wn + j * 16 + fm;
        fc(m, n, acc[i][j][r]);
      }
}

// ---------------- functors ----------------
struct FAB {
  const u16* p;
  int ld;
  __device__ __forceinline__ const u16* operator()(int r, int k) const {
    return p + (size_t)r * ld + k;
  }
};
// vh stored in q-buffer layout [B,H,L,Dh]; gather row m=(b,l), col k=h*1024+d
struct FAvh {
  const u16* q;
  __device__ __forceinline__ const u16* operator()(int m, int k) const {
    int b = m >> 11, l = m & 2047, h = k >> 10, kk = k & 1023;
    return q + ((size_t)((b << 1) + h) * 2048 + l) * 1024 + kk;
  }
};
struct EQKV {
  u16* qb;
  u16* kb;
  float* vout;
  const float* bias;
  __device__ __forceinline__ void operator()(int m, int n, float v) const {
    v += bias[n];
    int b = m >> 11, l = m & 2047;
    int part = n >> 11, nn = n & 2047, h = nn >> 10, d = nn & 1023;
    size_t idx = ((size_t)((b << 1) + h) * 2048 + l) * 1024 + d;
    if (part == 0)
      qb[idx] = f2b(v);
    else if (part == 1)
      kb[idx] = f2b(v);
    else
      vout[idx] = v;
  }
};
struct EScore {
  float* S;
  __device__ __forceinline__ void operator()(int m, int n, float v) const {
    S[((size_t)m << 11) + n] = v * 0.03125f + (n > m ? -1.0e9f : 0.0f);
  }
};
struct EBf16 {
  u16* o;
  int ld;
  __device__ __forceinline__ void operator()(int m, int n, float v) const {
    o[(size_t)m * ld + n] = f2b(v);
  }
};
struct EOut {
  float* o;
  const float* bias;
  __device__ __forceinline__ void operator()(int m, int n, float v) const {
    o[((size_t)m << 11) + n] = v + bias[n];
  }
};

// ---------------- kernels ----------------
__global__ void __launch_bounds__(256) k_cast(const float* in, u16* out) {
  int i = (blockIdx.x * 256 + threadIdx.x) * 4;
  float4 f = *(const float4*)(in + i);
  ushort4 o;
  o.x = f2b(f.x);
  o.y = f2b(f.y);
  o.z = f2b(f.z);
  o.w = f2b(f.w);
  *(ushort4*)(out + i) = o;
}

__global__ void __launch_bounds__(256) k_qkv(const u16* xb, const u16* wb,
                                             const float* bias, u16* qb,
                                             u16* kb, float* vout) {
  gemm128_body(FAB{xb, 2048}, FAB{wb, 2048}, EQKV{qb, kb, vout, bias},
               blockIdx.y * 128, blockIdx.x * 128, 2048);
}

__global__ void __launch_bounds__(256) k_rope(u16* qb, u16* kb, float* kout) {
  int row = blockIdx.x;  // bh*2048 + l
  int l = row & 2047;
  size_t base = (size_t)row * 1024;
  float lf = (float)l;
  const float c0 = (float)(-9.210340371976184 / 1024.0);  // -ln(1e4)/1024
  for (int i = threadIdx.x; i < 512; i += 256) {
    float inv = expf((float)(2 * i) * c0);
    float th = lf * inv;
    float c = cosf(th), s = sinf(th);
    float x1 = b2f(qb[base + i]), x2 = b2f(qb[base + 512 + i]);
    qb[base + i] = f2b(x1 * c - x2 * s);
    qb[base + 512 + i] = f2b(x1 * s + x2 * c);
    float y1 = b2f(kb[base + i]), y2 = b2f(kb[base + 512 + i]);
    float r1 = y1 * c - y2 * s, r2 = y1 * s + y2 * c;
    kb[base + i] = f2b(r1);
    kb[base + 512 + i] = f2b(r2);
    kout[base + i] = r1;
    kout[base + 512 + i] = r2;
  }
}

__global__ void __launch_bounds__(256) k_transpose_v(const float* v, u16* vt) {
  __shared__ u16 tile[64][65];
  int bh = blockIdx.z;
  int d0 = blockIdx.x * 64, l0 = blockIdx.y * 64;
  const float* vb = v + (size_t)bh * 2048 * 1024;
  u16* vtb = vt + (size_t)bh * 1024 * 2048;
  int t = threadIdx.x;
  int c = t & 63, r4 = t >> 6;
#pragma unroll
  for (int r = 0; r < 16; ++r) {
    int row = r * 4 + r4;
    tile[row][c] = f2b(vb[(size_t)(l0 + row) * 1024 + d0 + c]);
  }
  __syncthreads();
#pragma unroll
  for (int r = 0; r < 16; ++r) {
    int drow = r * 4 + r4;
    vtb[(size_t)(d0 + drow) * 2048 + l0 + c] = tile[c][drow];
  }
}

__global__ void __launch_bounds__(256) k_score(const u16* qb, const u16* kb,
                                               float* S, int zbase) {
  int m0 = blockIdx.y * 128, n0 = blockIdx.x * 128;
  if (n0 > m0) return;  // strictly-upper tile: fully masked, skipped
  int z = blockIdx.z, bh = zbase + z;
  const u16* q = qb + (size_t)bh * 2048 * 1024;
  const u16* k = kb + (size_t)bh * 2048 * 1024;
  float* Sz = S + (size_t)z * 2048 * 2048;
  gemm128_body(FAB{q, 1024}, FAB{k, 1024}, EScore{Sz}, m0, n0, 1024);
}

__global__ void __launch_bounds__(256) k_softmax(const float* S, u16* P) {
  int l = blockIdx.x, z = blockIdx.y;
  const float* Srow = S + ((size_t)z * 2048 + l) * 2048;
  u16* Prow = P + ((size_t)z * 2048 + l) * 2048;
  int t = threadIdx.x;
  int jend = ((l >> 7) + 1) << 7;
  __shared__ float red[4];
  float vals[8];
  float mx = -1e30f;
#pragma unroll
  for (int i = 0; i < 8; ++i) {
    int j = i * 256 + t;
    float v = (j <= l) ? Srow[j] : -1e30f;
    vals[i] = v;
    mx = fmaxf(mx, v);
  }
#pragma unroll
  for (int off = 32; off; off >>= 1) mx = fmaxf(mx, __shfl_down(mx, off));
  if ((t & 63) == 0) red[t >> 6] = mx;
  __syncthreads();
  mx = fmaxf(fmaxf(red[0], red[1]), fmaxf(red[2], red[3]));
  __syncthreads();
  float sum = 0.f;
#pragma unroll
  for (int i = 0; i < 8; ++i) {
    int j = i * 256 + t;
    float e = (j <= l) ? __expf(vals[i] - mx) : 0.f;
    vals[i] = e;
    sum += e;
  }
#pragma unroll
  for (int off = 32; off; off >>= 1) sum += __shfl_down(sum, off);
  if ((t & 63) == 0) red[t >> 6] = sum;
  __syncthreads();
  sum = red[0] + red[1] + red[2] + red[3];
  float is = 1.0f / sum;
#pragma unroll
  for (int i = 0; i < 8; ++i) {
    int j = i * 256 + t;
    if (j < jend) Prow[j] = f2b(vals[i] * is);
  }
}

__global__ void __launch_bounds__(256) k_pv(const u16* P, const u16* vt,
                                            u16* vh, int zbase) {
  int z = blockIdx.z, bh = zbase + z;
  int m0 = blockIdx.y * 128, n0 = blockIdx.x * 128;
  const u16* Pz = P + (size_t)z * 2048 * 2048;
  const u16* vtb = vt + (size_t)bh * 1024 * 2048;
  u16* outb = vh + (size_t)bh * 2048 * 1024;  // overwrites q[bh]: q is dead
  int Keff = m0 + 128;  // causal: P is zero-padded to the tile boundary
  gemm128_body(FAB{Pz, 2048}, FAB{vtb, 2048}, EBf16{outb, 1024}, m0, n0, Keff);
}

__global__ void __launch_bounds__(256) k_out(const u16* vh, const u16* w2,
                                             const float* bias, float* out) {
  gemm128_body(FAvh{vh}, FAB{w2, 2048}, EOut{out, bias}, blockIdx.y * 128,
               blockIdx.x * 128, 2048);
}

// ---------------- launch ----------------
extern "C" void kernel_launch(void* const* d_in, const int* in_sizes, int n_in,
                              void* d_out, int out_size, void* d_ws,
                              size_t ws_size, hipStream_t stream) {
  const float* x = (const float*)d_in[0];
  // d_in[1] = mask: causal 0/-1e9, reproduced analytically in EScore
  const float* w1 = (const float*)d_in[2];
  const float* b1 = (const float*)d_in[3];
  const float* w2 = (const float*)d_in[4];
  const float* b2 = (const float*)d_in[5];
  float* out = (float*)d_out;
  float* kout = out + (size_t)16777216;
  float* vout = kout + (size_t)16777216;

  char* ws = (char*)d_ws;
  u16* xb = (u16*)ws;
  ws += (size_t)33554432;
  u16* w1b = (u16*)ws;
  ws += (size_t)25165824;
  u16* w2b = (u16*)ws;
  ws += (size_t)8388608;
  u16* qb = (u16*)ws;  // doubles as vh after each pair's score GEMM
  ws += (size_t)33554432;
  u16* kb = (u16*)ws;
  ws += (size_t)33554432;
  u16* vtb = (u16*)ws;
  ws += (size_t)33554432;
  size_t used = (size_t)(ws - (char*)d_ws);
  size_t rem = ws_size > used ? ws_size - used : 0;
  size_t perz = (size_t)2048 * 2048 * 4 + (size_t)2048 * 2048 * 2;
  int Z = 1;
  if (rem >= 8 * perz)
    Z = 8;
  else if (rem >= 4 * perz)
    Z = 4;
  else if (rem >= 2 * perz)
    Z = 2;
  float* S = (float*)ws;
  u16* P = (u16*)(ws + (size_t)Z * 2048 * 2048 * 4);

  k_cast<<<16384, 256, 0, stream>>>(x, xb);
  k_cast<<<12288, 256, 0, stream>>>(w1, w1b);
  k_cast<<<4096, 256, 0, stream>>>(w2, w2b);
  k_qkv<<<dim3(48, 64), 256, 0, stream>>>(xb, w1b, b1, qb, kb, vout);
  k_rope<<<16384, 256, 0, stream>>>(qb, kb, kout);
  k_transpose_v<<<dim3(16, 32, 8), 256, 0, stream>>>(vout, vtb);
  for (int zb = 0; zb < 8; zb += Z) {
    k_score<<<dim3(16, 16, Z), 256, 0, stream>>>(qb, kb, S, zb);
    k_softmax<<<dim3(2048, Z), 256, 0, stream>>>(S, P);
    k_pv<<<dim3(8, 16, Z), 256, 0, stream>>>(P, vtb, qb, zb);
  }
  k_out<<<dim3(16, 64), 256, 0, stream>>>(qb, w2b, b2, out);
}

// Round 3
// 877.621 us; speedup vs baseline: 1.1239x; 1.0221x over previous
//
#include <hip/hip_runtime.h>
#include <hip/hip_bf16.h>
#include <math.h>

typedef unsigned short u16;
typedef __attribute__((ext_vector_type(8))) __bf16 bf16x8;
typedef __attribute__((ext_vector_type(4))) float f32x4;

__device__ __forceinline__ u16 f2b(float f) {
  unsigned u = __builtin_bit_cast(unsigned, f);
  u += 0x7fffu + ((u >> 16) & 1u);
  return (u16)(u >> 16);
}
__device__ __forceinline__ float b2f(u16 h) {
  unsigned u = ((unsigned)h) << 16;
  return __builtin_bit_cast(float, u);
}

__device__ __forceinline__ void gld_lds16(const u16* g, u16* l) {
  __builtin_amdgcn_global_load_lds(
      (const __attribute__((address_space(1))) unsigned int*)g,
      (__attribute__((address_space(3))) unsigned int*)l, 16, 0, 0);
}

// ---------------- generic 128x128 BT-form GEMM tile body (m97 structure) ----
// C[m][n] = sum_k A[m][k] * B[n][k], K multiple of 64, tiles 128x128, 256 thr.
// LDS XOR-swizzled (r1 win: physical 16B-chunk p of row r holds chunk p^(r&7);
// global_load_lds can't pad, swizzle is the only conflict fix — verified
// SQ_LDS_BANK_CONFLICT 7.55e7 -> 0).
// Staging addresses are expressed as scalar_base + lane-invariant offset +
// loop-scalar k0 so the compiler can keep per-iter address advance on SALU.
template <class FC>
__device__ __forceinline__ void gemm128_body(const u16* A, int lda,
                                             const u16* B, int ldb, FC fc,
                                             int m0, int n0, int K) {
  __shared__ __align__(16) u16 As[128 * 64];
  __shared__ __align__(16) u16 Bs[128 * 64];
  const int tid = threadIdx.x;
  const int wave = tid >> 6;
  const int lane = tid & 63;
  const int srow = lane >> 3;                // 0..7 row within chunk
  const int scol = ((lane & 7) ^ srow) * 8;  // swizzled global 16B chunk
  const int wm = (wave & 1) * 64;
  const int wn = (wave >> 1) * 64;
  const int fm = lane & 15;
  const int fs = fm & 7;  // read-side swizzle key

  const u16* Abase = A + (size_t)m0 * lda;
  const u16* Bbase = B + (size_t)n0 * ldb;
  const size_t aLane = (size_t)(wave * 8 + srow) * lda + scol;
  const size_t bLane = (size_t)(wave * 8 + srow) * ldb + scol;

  f32x4 acc[4][4];
#pragma unroll
  for (int i = 0; i < 4; ++i)
#pragma unroll
    for (int j = 0; j < 4; ++j) acc[i][j] = (f32x4){0.f, 0.f, 0.f, 0.f};

  for (int k0 = 0; k0 < K; k0 += 64) {
#pragma unroll
    for (int c = 0; c < 4; ++c) {
      gld_lds16(Abase + (aLane + (size_t)(c * 32) * lda + k0),
                &As[(c * 4 + wave) * 512]);
      gld_lds16(Bbase + (bLane + (size_t)(c * 32) * ldb + k0),
                &Bs[(c * 4 + wave) * 512]);
    }
    __syncthreads();
#pragma unroll
    for (int kk = 0; kk < 2; ++kk) {
      const int cb = kk * 4 + (lane >> 4);  // logical 16B chunk
      const int p8 = (cb ^ fs) * 8;         // physical element offset
      bf16x8 af[4], bfr[4];
#pragma unroll
      for (int i = 0; i < 4; ++i)
        af[i] = *(const bf16x8*)&As[(wm + i * 16 + fm) * 64 + p8];
#pragma unroll
      for (int j = 0; j < 4; ++j)
        bfr[j] = *(const bf16x8*)&Bs[(wn + j * 16 + fm) * 64 + p8];
#pragma unroll
      for (int i = 0; i < 4; ++i)
#pragma unroll
        for (int j = 0; j < 4; ++j)
          acc[i][j] = __builtin_amdgcn_mfma_f32_16x16x32_bf16(
              af[i], bfr[j], acc[i][j], 0, 0, 0);
    }
    __syncthreads();
  }
  const int er = lane >> 4;
#pragma unroll
  for (int i = 0; i < 4; ++i)
#pragma unroll
    for (int j = 0; j < 4; ++j)
#pragma unroll
      for (int r = 0; r < 4; ++r) {
        int m = m0 + wm + i * 16 + er * 4 + r;
        int n = n0 + wn + j * 16 + fm;
        fc(m, n, acc[i][j][r]);
      }
}

// ---------------- epilogue functors ----------------
struct EQKV {
  u16* qb;
  u16* kb;
  float* vout;
  const float* bias;
  __device__ __forceinline__ void operator()(int m, int n, float v) const {
    v += bias[n];
    int b = m >> 11, l = m & 2047;
    int part = n >> 11, nn = n & 2047, h = nn >> 10, d = nn & 1023;
    size_t idx = ((size_t)((b << 1) + h) * 2048 + l) * 1024 + d;
    if (part == 0)
      qb[idx] = f2b(v);
    else if (part == 1)
      kb[idx] = f2b(v);
    else
      vout[idx] = v;
  }
};
struct EScore {
  float* S;
  __device__ __forceinline__ void operator()(int m, int n, float v) const {
    S[((size_t)m << 11) + n] = v * 0.03125f + (n > m ? -1.0e9f : 0.0f);
  }
};
struct EBf16 {
  u16* o;
  int ld;
  __device__ __forceinline__ void operator()(int m, int n, float v) const {
    o[(size_t)m * ld + n] = f2b(v);
  }
};
struct EOut {
  float* o;
  const float* bias;
  __device__ __forceinline__ void operator()(int m, int n, float v) const {
    o[((size_t)m << 11) + n] = v + bias[n];
  }
};

// ---------------- kernels ----------------
__global__ void __launch_bounds__(256) k_cast3(const float* x, const float* w1,
                                               const float* w2, u16* xb,
                                               u16* w1b, u16* w2b) {
  long i = (long)(blockIdx.x * 256 + threadIdx.x) * 4;
  const float* src;
  u16* dst;
  long off;
  if (i < 16777216L) {
    src = x; dst = xb; off = i;
  } else if (i < 16777216L + 12582912L) {
    src = w1; dst = w1b; off = i - 16777216L;
  } else {
    src = w2; dst = w2b; off = i - 16777216L - 12582912L;
  }
  float4 f = *(const float4*)(src + off);
  ushort4 o;
  o.x = f2b(f.x);
  o.y = f2b(f.y);
  o.z = f2b(f.z);
  o.w = f2b(f.w);
  *(ushort4*)(dst + off) = o;
}

__global__ void __launch_bounds__(256) k_qkv(const u16* xb, const u16* wb,
                                             const float* bias, u16* qb,
                                             u16* kb, float* vout) {
  gemm128_body(xb, 2048, wb, 2048, EQKV{qb, kb, vout, bias}, blockIdx.y * 128,
               blockIdx.x * 128, 2048);
}

// one block per position l; cos/sin computed once, shared across all 8 bh rows
__global__ void __launch_bounds__(256) k_rope(u16* qb, u16* kb, float* kout) {
  int l = blockIdx.x;
  int t = threadIdx.x;
  float lf = (float)l;
  const float c0 = (float)(-9.210340371976184 / 1024.0);  // -ln(1e4)/1024
  float s0, c_0, s1, c_1;
  {
    float inv = __expf((float)(2 * t) * c0);
    __sincosf(lf * inv, &s0, &c_0);
    float inv2 = __expf((float)(2 * (t + 256)) * c0);
    __sincosf(lf * inv2, &s1, &c_1);
  }
#pragma unroll
  for (int bh = 0; bh < 8; ++bh) {
    size_t base = ((size_t)bh * 2048 + l) * 1024;
#pragma unroll
    for (int half = 0; half < 2; ++half) {
      int i = t + half * 256;
      float c = half ? c_1 : c_0;
      float s = half ? s1 : s0;
      float x1 = b2f(qb[base + i]), x2 = b2f(qb[base + 512 + i]);
      qb[base + i] = f2b(x1 * c - x2 * s);
      qb[base + 512 + i] = f2b(x1 * s + x2 * c);
      float y1 = b2f(kb[base + i]), y2 = b2f(kb[base + 512 + i]);
      float r1 = y1 * c - y2 * s, r2 = y1 * s + y2 * c;
      kb[base + i] = f2b(r1);
      kb[base + 512 + i] = f2b(r2);
      kout[base + i] = r1;
      kout[base + 512 + i] = r2;
    }
  }
}

__global__ void __launch_bounds__(256) k_transpose_v(const float* v, u16* vt) {
  __shared__ u16 tile[64][65];
  int bh = blockIdx.z;
  int d0 = blockIdx.x * 64, l0 = blockIdx.y * 64;
  const float* vb = v + (size_t)bh * 2048 * 1024;
  u16* vtb = vt + (size_t)bh * 1024 * 2048;
  int t = threadIdx.x;
  int c = t & 63, r4 = t >> 6;
#pragma unroll
  for (int r = 0; r < 16; ++r) {
    int row = r * 4 + r4;
    tile[row][c] = f2b(vb[(size_t)(l0 + row) * 1024 + d0 + c]);
  }
  __syncthreads();
#pragma unroll
  for (int r = 0; r < 16; ++r) {
    int drow = r * 4 + r4;
    vtb[(size_t)(d0 + drow) * 2048 + l0 + c] = tile[c][drow];
  }
}

__global__ void __launch_bounds__(256) k_score(const u16* qb, const u16* kb,
                                               float* S, int zbase) {
  int m0 = blockIdx.y * 128, n0 = blockIdx.x * 128;
  if (n0 > m0) return;  // strictly-upper tile: fully masked, skipped
  int z = blockIdx.z, bh = zbase + z;
  const u16* q = qb + (size_t)bh * 2048 * 1024;
  const u16* k = kb + (size_t)bh * 2048 * 1024;
  float* Sz = S + (size_t)z * 2048 * 2048;
  gemm128_body(q, 1024, k, 1024, EScore{Sz}, m0, n0, 1024);
}

__global__ void __launch_bounds__(256) k_softmax(const float* S, u16* P) {
  int l = blockIdx.x, z = blockIdx.y;
  const float* Srow = S + ((size_t)z * 2048 + l) * 2048;
  u16* Prow = P + ((size_t)z * 2048 + l) * 2048;
  int t = threadIdx.x;
  int jend = ((l >> 7) + 1) << 7;
  __shared__ float red[4];
  float vals[8];
  float mx = -1e30f;
#pragma unroll
  for (int i = 0; i < 8; ++i) {
    int j = i * 256 + t;
    float v = (j <= l) ? Srow[j] : -1e30f;
    vals[i] = v;
    mx = fmaxf(mx, v);
  }
#pragma unroll
  for (int off = 32; off; off >>= 1) mx = fmaxf(mx, __shfl_down(mx, off));
  if ((t & 63) == 0) red[t >> 6] = mx;
  __syncthreads();
  mx = fmaxf(fmaxf(red[0], red[1]), fmaxf(red[2], red[3]));
  __syncthreads();
  float sum = 0.f;
#pragma unroll
  for (int i = 0; i < 8; ++i) {
    int j = i * 256 + t;
    float e = (j <= l) ? __expf(vals[i] - mx) : 0.f;
    vals[i] = e;
    sum += e;
  }
#pragma unroll
  for (int off = 32; off; off >>= 1) sum += __shfl_down(sum, off);
  if ((t & 63) == 0) red[t >> 6] = sum;
  __syncthreads();
  sum = red[0] + red[1] + red[2] + red[3];
  float is = 1.0f / sum;
#pragma unroll
  for (int i = 0; i < 8; ++i) {
    int j = i * 256 + t;
    if (j < jend) Prow[j] = f2b(vals[i] * is);
  }
}

// vh written in [B, L, H*Dh] layout so out-proj's A-side is a plain row
__global__ void __launch_bounds__(256) k_pv(const u16* P, const u16* vt,
                                            u16* vh, int zbase) {
  int z = blockIdx.z, bh = zbase + z;
  int b = bh >> 1, h = bh & 1;
  int m0 = blockIdx.y * 128, n0 = blockIdx.x * 128;
  const u16* Pz = P + (size_t)z * 2048 * 2048;
  const u16* vtb = vt + (size_t)bh * 1024 * 2048;
  u16* outb = vh + (size_t)b * 2048 * 2048 + (size_t)h * 1024;
  int Keff = m0 + 128;  // causal: P is zero-padded to the tile boundary
  gemm128_body(Pz, 2048, vtb, 2048, EBf16{outb, 2048}, m0, n0, Keff);
}

__global__ void __launch_bounds__(256) k_out(const u16* vh, const u16* w2,
                                             const float* bias, float* out) {
  gemm128_body(vh, 2048, w2, 2048, EOut{out, bias}, blockIdx.y * 128,
               blockIdx.x * 128, 2048);
}

// ---------------- launch ----------------
extern "C" void kernel_launch(void* const* d_in, const int* in_sizes, int n_in,
                              void* d_out, int out_size, void* d_ws,
                              size_t ws_size, hipStream_t stream) {
  const float* x = (const float*)d_in[0];
  // d_in[1] = mask: causal 0/-1e9, reproduced analytically in EScore
  const float* w1 = (const float*)d_in[2];
  const float* b1 = (const float*)d_in[3];
  const float* w2 = (const float*)d_in[4];
  const float* b2 = (const float*)d_in[5];
  float* out = (float*)d_out;
  float* kout = out + (size_t)16777216;
  float* vout = kout + (size_t)16777216;

  char* ws = (char*)d_ws;
  u16* xb = (u16*)ws;
  ws += (size_t)33554432;
  u16* w1b = (u16*)ws;
  ws += (size_t)25165824;
  u16* w2b = (u16*)ws;
  ws += (size_t)8388608;
  u16* qb = (u16*)ws;
  ws += (size_t)33554432;
  u16* kb = (u16*)ws;
  ws += (size_t)33554432;
  u16* vtb = (u16*)ws;
  ws += (size_t)33554432;
  u16* vh = (u16*)ws;
  ws += (size_t)33554432;
  size_t used = (size_t)(ws - (char*)d_ws);
  size_t rem = ws_size > used ? ws_size - used : 0;
  size_t perz = (size_t)2048 * 2048 * 4 + (size_t)2048 * 2048 * 2;
  int Z = 1;
  if (rem >= 8 * perz)
    Z = 8;
  else if (rem >= 4 * perz)
    Z = 4;
  else if (rem >= 2 * perz)
    Z = 2;
  float* S = (float*)ws;
  u16* P = (u16*)(ws + (size_t)Z * 2048 * 2048 * 4);

  k_cast3<<<32768, 256, 0, stream>>>(x, w1, w2, xb, w1b, w2b);
  k_qkv<<<dim3(48, 64), 256, 0, stream>>>(xb, w1b, b1, qb, kb, vout);
  k_rope<<<2048, 256, 0, stream>>>(qb, kb, kout);
  k_transpose_v<<<dim3(16, 32, 8), 256, 0, stream>>>(vout, vtb);
  for (int zb = 0; zb < 8; zb += Z) {
    k_score<<<dim3(16, 16, Z), 256, 0, stream>>>(qb, kb, S, zb);
    k_softmax<<<dim3(2048, Z), 256, 0, stream>>>(S, P);
    k_pv<<<dim3(8, 16, Z), 256, 0, stream>>>(P, vtb, vh, zb);
  }
  k_out<<<dim3(16, 64), 256, 0, stream>>>(vh, w2b, b2, out);
}

// Round 4
// 860.794 us; speedup vs baseline: 1.1458x; 1.0195x over previous
//
#include <hip/hip_runtime.h>
#include <hip/hip_bf16.h>
#include <math.h>

typedef unsigned short u16;
typedef __attribute__((ext_vector_type(8))) __bf16 bf16x8;
typedef __attribute__((ext_vector_type(4))) float f32x4;

__device__ __forceinline__ u16 f2b(float f) {
  unsigned u = __builtin_bit_cast(unsigned, f);
  u += 0x7fffu + ((u >> 16) & 1u);
  return (u16)(u >> 16);
}
__device__ __forceinline__ float b2f(u16 h) {
  unsigned u = ((unsigned)h) << 16;
  return __builtin_bit_cast(float, u);
}

__device__ __forceinline__ void gld_lds16(const u16* g, u16* l) {
  __builtin_amdgcn_global_load_lds(
      (const __attribute__((address_space(1))) unsigned int*)g,
      (__attribute__((address_space(3))) unsigned int*)l, 16, 0, 0);
}

// ---------------- generic 128x128 BT-form GEMM tile body (m97 structure) ----
// C[m][n] = sum_k A[m][k] * B[n][k], K multiple of 64, tiles 128x128, 256 thr.
// LDS XOR-swizzled (r1 win: conflicts 7.55e7 -> 0). Staging addresses kept
// scalar_base + lane-invariant + k0 for SALU advance (r3 win: VALU 36->23%).
template <class FC>
__device__ __forceinline__ void gemm128_body(const u16* A, int lda,
                                             const u16* B, int ldb, FC fc,
                                             int m0, int n0, int K) {
  __shared__ __align__(16) u16 As[128 * 64];
  __shared__ __align__(16) u16 Bs[128 * 64];
  const int tid = threadIdx.x;
  const int wave = tid >> 6;
  const int lane = tid & 63;
  const int srow = lane >> 3;                // 0..7 row within chunk
  const int scol = ((lane & 7) ^ srow) * 8;  // swizzled global 16B chunk
  const int wm = (wave & 1) * 64;
  const int wn = (wave >> 1) * 64;
  const int fm = lane & 15;
  const int fs = fm & 7;  // read-side swizzle key

  const u16* Abase = A + (size_t)m0 * lda;
  const u16* Bbase = B + (size_t)n0 * ldb;
  const size_t aLane = (size_t)(wave * 8 + srow) * lda + scol;
  const size_t bLane = (size_t)(wave * 8 + srow) * ldb + scol;

  f32x4 acc[4][4];
#pragma unroll
  for (int i = 0; i < 4; ++i)
#pragma unroll
    for (int j = 0; j < 4; ++j) acc[i][j] = (f32x4){0.f, 0.f, 0.f, 0.f};

  for (int k0 = 0; k0 < K; k0 += 64) {
#pragma unroll
    for (int c = 0; c < 4; ++c) {
      gld_lds16(Abase + (aLane + (size_t)(c * 32) * lda + k0),
                &As[(c * 4 + wave) * 512]);
      gld_lds16(Bbase + (bLane + (size_t)(c * 32) * ldb + k0),
                &Bs[(c * 4 + wave) * 512]);
    }
    __syncthreads();
#pragma unroll
    for (int kk = 0; kk < 2; ++kk) {
      const int cb = kk * 4 + (lane >> 4);  // logical 16B chunk
      const int p8 = (cb ^ fs) * 8;         // physical element offset
      bf16x8 af[4], bfr[4];
#pragma unroll
      for (int i = 0; i < 4; ++i)
        af[i] = *(const bf16x8*)&As[(wm + i * 16 + fm) * 64 + p8];
#pragma unroll
      for (int j = 0; j < 4; ++j)
        bfr[j] = *(const bf16x8*)&Bs[(wn + j * 16 + fm) * 64 + p8];
#pragma unroll
      for (int i = 0; i < 4; ++i)
#pragma unroll
        for (int j = 0; j < 4; ++j)
          acc[i][j] = __builtin_amdgcn_mfma_f32_16x16x32_bf16(
              af[i], bfr[j], acc[i][j], 0, 0, 0);
    }
    __syncthreads();
  }
  const int er = lane >> 4;
#pragma unroll
  for (int i = 0; i < 4; ++i)
#pragma unroll
    for (int j = 0; j < 4; ++j)
#pragma unroll
      for (int r = 0; r < 4; ++r) {
        int m = m0 + wm + i * 16 + er * 4 + r;
        int n = n0 + wn + j * 16 + fm;
        fc(m, n, acc[i][j][r]);
      }
}

// ---------------- epilogue functors ----------------
struct EQKV {
  u16* qb;
  u16* kb;
  float* vout;
  const float* bias;
  __device__ __forceinline__ void operator()(int m, int n, float v) const {
    v += bias[n];
    int b = m >> 11, l = m & 2047;
    int part = n >> 11, nn = n & 2047, h = nn >> 10, d = nn & 1023;
    size_t idx = ((size_t)((b << 1) + h) * 2048 + l) * 1024 + d;
    if (part == 0)
      qb[idx] = f2b(v);
    else if (part == 1)
      kb[idx] = f2b(v);
    else
      vout[idx] = v;
  }
};
// scores written bf16 (P is bf16 anyway; only pre-softmax quantization added)
struct EScoreB {
  u16* S;
  __device__ __forceinline__ void operator()(int m, int n, float v) const {
    S[((size_t)m << 11) + n] = f2b(v * 0.03125f + (n > m ? -1.0e9f : 0.0f));
  }
};
struct EBf16 {
  u16* o;
  int ld;
  __device__ __forceinline__ void operator()(int m, int n, float v) const {
    o[(size_t)m * ld + n] = f2b(v);
  }
};
struct EOut {
  float* o;
  const float* bias;
  __device__ __forceinline__ void operator()(int m, int n, float v) const {
    o[((size_t)m << 11) + n] = v + bias[n];
  }
};

// per-z S/P scratch: z<4 overlays dead xb/w1b region, z>=4 in tail region
__device__ __forceinline__ u16* spz(u16* sp0, u16* sp1, int z) {
  return (z < 4) ? sp0 + (size_t)z * 4194304 : sp1 + (size_t)(z - 4) * 4194304;
}

// ---------------- kernels ----------------
__global__ void __launch_bounds__(256) k_cast3(const float* x, const float* w1,
                                               const float* w2, u16* xb,
                                               u16* w1b, u16* w2b) {
  long i = (long)(blockIdx.x * 256 + threadIdx.x) * 4;
  const float* src;
  u16* dst;
  long off;
  if (i < 16777216L) {
    src = x; dst = xb; off = i;
  } else if (i < 16777216L + 12582912L) {
    src = w1; dst = w1b; off = i - 16777216L;
  } else {
    src = w2; dst = w2b; off = i - 16777216L - 12582912L;
  }
  float4 f = *(const float4*)(src + off);
  ushort4 o;
  o.x = f2b(f.x);
  o.y = f2b(f.y);
  o.z = f2b(f.z);
  o.w = f2b(f.w);
  *(ushort4*)(dst + off) = o;
}

__global__ void __launch_bounds__(256) k_qkv(const u16* xb, const u16* wb,
                                             const float* bias, u16* qb,
                                             u16* kb, float* vout) {
  gemm128_body(xb, 2048, wb, 2048, EQKV{qb, kb, vout, bias}, blockIdx.y * 128,
               blockIdx.x * 128, 2048);
}

// one block per position l; cos/sin computed once, shared across all 8 bh rows
__global__ void __launch_bounds__(256) k_rope(u16* qb, u16* kb, float* kout) {
  int l = blockIdx.x;
  int t = threadIdx.x;
  float lf = (float)l;
  const float c0 = (float)(-9.210340371976184 / 1024.0);  // -ln(1e4)/1024
  float s0, c_0, s1, c_1;
  {
    float inv = __expf((float)(2 * t) * c0);
    __sincosf(lf * inv, &s0, &c_0);
    float inv2 = __expf((float)(2 * (t + 256)) * c0);
    __sincosf(lf * inv2, &s1, &c_1);
  }
#pragma unroll
  for (int bh = 0; bh < 8; ++bh) {
    size_t base = ((size_t)bh * 2048 + l) * 1024;
#pragma unroll
    for (int half = 0; half < 2; ++half) {
      int i = t + half * 256;
      float c = half ? c_1 : c_0;
      float s = half ? s1 : s0;
      float x1 = b2f(qb[base + i]), x2 = b2f(qb[base + 512 + i]);
      qb[base + i] = f2b(x1 * c - x2 * s);
      qb[base + 512 + i] = f2b(x1 * s + x2 * c);
      float y1 = b2f(kb[base + i]), y2 = b2f(kb[base + 512 + i]);
      float r1 = y1 * c - y2 * s, r2 = y1 * s + y2 * c;
      kb[base + i] = f2b(r1);
      kb[base + 512 + i] = f2b(r2);
      kout[base + i] = r1;
      kout[base + 512 + i] = r2;
    }
  }
}

__global__ void __launch_bounds__(256) k_transpose_v(const float* v, u16* vt) {
  __shared__ u16 tile[64][65];
  int bh = blockIdx.z;
  int d0 = blockIdx.x * 64, l0 = blockIdx.y * 64;
  const float* vb = v + (size_t)bh * 2048 * 1024;
  u16* vtb = vt + (size_t)bh * 1024 * 2048;
  int t = threadIdx.x;
  int c = t & 63, r4 = t >> 6;
#pragma unroll
  for (int r = 0; r < 16; ++r) {
    int row = r * 4 + r4;
    tile[row][c] = f2b(vb[(size_t)(l0 + row) * 1024 + d0 + c]);
  }
  __syncthreads();
#pragma unroll
  for (int r = 0; r < 16; ++r) {
    int drow = r * 4 + r4;
    vtb[(size_t)(d0 + drow) * 2048 + l0 + c] = tile[c][drow];
  }
}

__global__ void __launch_bounds__(256) k_score(const u16* qb, const u16* kb,
                                               u16* sp0, u16* sp1) {
  int m0 = blockIdx.y * 128, n0 = blockIdx.x * 128;
  if (n0 > m0) return;  // strictly-upper tile: fully masked, skipped
  int z = blockIdx.z;
  const u16* q = qb + (size_t)z * 2048 * 1024;
  const u16* k = kb + (size_t)z * 2048 * 1024;
  gemm128_body(q, 1024, k, 1024, EScoreB{spz(sp0, sp1, z)}, m0, n0, 1024);
}

// in-place: reads bf16 scores, writes bf16 probs to the same buffer
__global__ void __launch_bounds__(256) k_softmax(u16* sp0, u16* sp1) {
  int l = blockIdx.x, z = blockIdx.y;
  u16* row = spz(sp0, sp1, z) + ((size_t)l << 11);
  int t = threadIdx.x;
  int jend = ((l >> 7) + 1) << 7;
  __shared__ float red[4];
  float vals[8];
  float mx = -1e30f;
#pragma unroll
  for (int i = 0; i < 8; ++i) {
    int j = i * 256 + t;
    float v = (j <= l) ? b2f(row[j]) : -1e30f;
    vals[i] = v;
    mx = fmaxf(mx, v);
  }
#pragma unroll
  for (int off = 32; off; off >>= 1) mx = fmaxf(mx, __shfl_down(mx, off));
  if ((t & 63) == 0) red[t >> 6] = mx;
  __syncthreads();
  mx = fmaxf(fmaxf(red[0], red[1]), fmaxf(red[2], red[3]));
  __syncthreads();
  float sum = 0.f;
#pragma unroll
  for (int i = 0; i < 8; ++i) {
    int j = i * 256 + t;
    float e = (j <= l) ? __expf(vals[i] - mx) : 0.f;
    vals[i] = e;
    sum += e;
  }
#pragma unroll
  for (int off = 32; off; off >>= 1) sum += __shfl_down(sum, off);
  if ((t & 63) == 0) red[t >> 6] = sum;
  __syncthreads();
  sum = red[0] + red[1] + red[2] + red[3];
  float is = 1.0f / sum;
#pragma unroll
  for (int i = 0; i < 8; ++i) {
    int j = i * 256 + t;
    if (j < jend) row[j] = f2b(vals[i] * is);
  }
}

// vh overlays qb (q dead after k_score; kernel boundary orders all z).
// vh layout [B, L, H*Dh] so out-proj's A-side is a plain row.
__global__ void __launch_bounds__(256) k_pv(u16* sp0, u16* sp1, const u16* vt,
                                            u16* vh) {
  int z = blockIdx.z;
  int b = z >> 1, h = z & 1;
  int m0 = blockIdx.y * 128, n0 = blockIdx.x * 128;
  const u16* Pz = spz(sp0, sp1, z);
  const u16* vtb = vt + (size_t)z * 1024 * 2048;
  u16* outb = vh + (size_t)b * 2048 * 2048 + (size_t)h * 1024;
  int Keff = m0 + 128;  // causal: P is zero-padded to the tile boundary
  gemm128_body(Pz, 2048, vtb, 2048, EBf16{outb, 2048}, m0, n0, Keff);
}

__global__ void __launch_bounds__(256) k_out(const u16* vh, const u16* w2,
                                             const float* bias, float* out) {
  gemm128_body(vh, 2048, w2, 2048, EOut{out, bias}, blockIdx.y * 128,
               blockIdx.x * 128, 2048);
}

// ---------------- launch ----------------
extern "C" void kernel_launch(void* const* d_in, const int* in_sizes, int n_in,
                              void* d_out, int out_size, void* d_ws,
                              size_t ws_size, hipStream_t stream) {
  const float* x = (const float*)d_in[0];
  // d_in[1] = mask: causal 0/-1e9, reproduced analytically in EScoreB
  const float* w1 = (const float*)d_in[2];
  const float* b1 = (const float*)d_in[3];
  const float* w2 = (const float*)d_in[4];
  const float* b2 = (const float*)d_in[5];
  float* out = (float*)d_out;
  float* kout = out + (size_t)16777216;
  float* vout = kout + (size_t)16777216;

  // ws layout (201.3 MB total):
  // [xb 33.5][w1b 25.2][w2b 8.4][qb 33.5][kb 33.5][vtb 33.5][sp1 33.5]
  // xb+w1b are dead after k_qkv -> S/P scratch for z=0..3 overlays them;
  // z=4..7 use sp1 tail. qb is dead after k_score -> vh overlays it.
  char* ws = (char*)d_ws;
  u16* xb = (u16*)ws;
  ws += (size_t)33554432;
  u16* w1b = (u16*)ws;
  ws += (size_t)25165824;
  u16* w2b = (u16*)ws;
  ws += (size_t)8388608;
  u16* qb = (u16*)ws;
  ws += (size_t)33554432;
  u16* kb = (u16*)ws;
  ws += (size_t)33554432;
  u16* vtb = (u16*)ws;
  ws += (size_t)33554432;
  u16* sp1 = (u16*)ws;
  u16* sp0 = xb;  // overlays xb+w1b (58.7 MB >= 4*8.4 MB)
  u16* vh = qb;   // overlays qb

  k_cast3<<<32768, 256, 0, stream>>>(x, w1, w2, xb, w1b, w2b);
  k_qkv<<<dim3(48, 64), 256, 0, stream>>>(xb, w1b, b1, qb, kb, vout);
  k_rope<<<2048, 256, 0, stream>>>(qb, kb, kout);
  k_transpose_v<<<dim3(16, 32, 8), 256, 0, stream>>>(vout, vtb);
  k_score<<<dim3(16, 16, 8), 256, 0, stream>>>(qb, kb, sp0, sp1);
  k_softmax<<<dim3(2048, 8), 256, 0, stream>>>(sp0, sp1);
  k_pv<<<dim3(8, 16, 8), 256, 0, stream>>>(sp0, sp1, vtb, vh);
  k_out<<<dim3(16, 64), 256, 0, stream>>>(vh, w2b, b2, out);
}